// Round 9
// baseline (194.774 us; speedup 1.0000x reference)
//
#include <hip/hip_runtime.h>
#include <hip/hip_bf16.h>
#include <cstdint>
#include <cstddef>

typedef __bf16 bf16_t;
typedef __bf16 bf16x8 __attribute__((ext_vector_type(8)));
typedef __bf16 bf16x4 __attribute__((ext_vector_type(4)));
typedef float f32x4 __attribute__((ext_vector_type(4)));
typedef _Float16 f16x8 __attribute__((ext_vector_type(8)));

#define DEVINL __device__ __forceinline__

DEVINL void gload_lds16(const bf16_t* g, bf16_t* l) {
  __builtin_amdgcn_global_load_lds(
      (__attribute__((address_space(1))) void*)(g),
      (__attribute__((address_space(3))) void*)(l), 16, 0, 0);
}

// ---------------------------------------------------------------------------
// cast fp32 -> bf16
// ---------------------------------------------------------------------------
__global__ __launch_bounds__(256) void cast_f32_bf16(
    const float* __restrict__ in, bf16_t* __restrict__ out, long n) {
  long i = ((long)blockIdx.x * 256 + threadIdx.x) * 4;
  if (i + 3 < n) {
    float4 v = *reinterpret_cast<const float4*>(in + i);
    bf16x4 o = { (bf16_t)v.x, (bf16_t)v.y, (bf16_t)v.z, (bf16_t)v.w };
    *reinterpret_cast<bf16x4*>(out + i) = o;
  }
}

// ---------------------------------------------------------------------------
// W [1024][3072] fp32 -> Wt [3072][1024] bf16
// ---------------------------------------------------------------------------
__global__ __launch_bounds__(256) void transpose_W(
    const float* __restrict__ W, bf16_t* __restrict__ Wt) {
  __shared__ bf16_t tile[64][66];
  const int c0 = blockIdx.x * 64, r0 = blockIdx.y * 64;
  const int tc = threadIdx.x & 63, tr = threadIdx.x >> 6;
#pragma unroll
  for (int k = 0; k < 16; ++k) {
    int rl = k * 4 + tr;
    tile[rl][tc] = (bf16_t)W[(size_t)(r0 + rl) * 3072 + c0 + tc];
  }
  __syncthreads();
#pragma unroll
  for (int k = 0; k < 16; ++k) {
    int cl = k * 4 + tr;
    Wt[(size_t)(c0 + cl) * 1024 + r0 + tc] = tile[tc][cl];
  }
}

// ---------------------------------------------------------------------------
// dense V [8192][1024] -> Vt [b][h][n] bf16
// ---------------------------------------------------------------------------
__global__ __launch_bounds__(256) void transpose_V(
    const bf16_t* __restrict__ V, bf16_t* __restrict__ Vt) {
  __shared__ bf16_t tile[64][66];
  const int b = blockIdx.z;
  const int h0 = blockIdx.x * 64, n0 = blockIdx.y * 64;
  const int tc = threadIdx.x & 63, tr = threadIdx.x >> 6;
#pragma unroll
  for (int k = 0; k < 16; ++k) {
    int nl = k * 4 + tr;
    tile[nl][tc] = V[((size_t)b * 2048 + n0 + nl) * 1024 + h0 + tc];
  }
  __syncthreads();
#pragma unroll
  for (int k = 0; k < 16; ++k) {
    int hl = k * 4 + tr;
    Vt[((size_t)b * 1024 + h0 + hl) * 2048 + n0 + tc] = tile[tc][hl];
  }
}

// ---------------------------------------------------------------------------
// gemm_roll: C[M][N] = A[M][K] @ B[N][K]^T.  Tile (MR*32)x128, 4 waves
// (2 M x 2 N), BK=32, ROLLED runtime K-loop (~150-instr body: fixes the
// I-cache thrash of the fully-unrolled R7/R8 variants), 2-slot LDS double
// buffer (s=q&1). Per iter: issue next tile's gload_lds | 8 ds_read frags
// (T2 swizzle, conflict-free) | 16(8) MFMA under setprio | lgkmcnt(0) |
// vmcnt(0) | ONE barrier (publishes tile q+1 AND frees slot s).
// Band rasterization (R8) retained: XCD chunk + GM=8 M-bands, i fastest.
// EPI 0: bf16 dense Q|K|V segs (seg=n0>>10, Q scaled 1/32, +bias)
// EPI 1: fp32 out.   EPI 2: fp16 out.
// ---------------------------------------------------------------------------
template <int EPI, int MR>
__global__ __launch_bounds__(256, 4) void gemm_roll(
    const bf16_t* __restrict__ A, const bf16_t* __restrict__ B,
    void* __restrict__ C, const float* __restrict__ bias,
    int lda, int ldb, int ldc, long sA, long sB, long sC, int K) {
  constexpr int BM = MR * 32;           // 128 or 64
  constexpr int HTE = (BM + 128) * 32;  // elems per slot
  __shared__ bf16_t lds[2][HTE];        // [slot][A BMx32 | B 128x32]

  // XCD chunk + L2 band rasterization (nwg%8==0, gy%8==0 for all grids)
  constexpr int GM = 8;
  const int gx = gridDim.x, gy = gridDim.y;
  const int nwg = gx * gy * gridDim.z;
  const int flat = blockIdx.x + gx * (blockIdx.y + gy * blockIdx.z);
  const int v = (flat & 7) * (nwg >> 3) + (flat >> 3);
  const int slice = gx * gy;
  const int bz = v / slice;
  const int rr = v % slice;
  const int BS = GM * gx;
  const int band = rr / BS, tt = rr % BS;
  const int bx = tt / GM;
  const int by = band * GM + (tt % GM);

  const int m0 = by * BM, n0 = bx * 128;
  A += (size_t)bz * sA;
  B += (size_t)bz * sB;

  const int tid = threadIdx.x;
  const int w = tid >> 6, lane = tid & 63;
  const int wr = w >> 1, wc = w & 1;

  // staging source: row = lane>>2, k-chunk = (lane&3)^((lane>>3)&3)  (T2)
  const int srow = lane >> 2;
  const int schunk = ((lane & 3) ^ ((lane >> 3) & 3)) * 8;
  const bf16_t* gA = A + (size_t)(m0 + w * (MR * 8) + srow) * lda + schunk;
  const bf16_t* gB = B + (size_t)(n0 + w * 32 + srow) * ldb + schunk;

  const int rsel = lane & 15, kg = lane >> 4;
  const int kswz = (kg ^ ((rsel >> 1) & 3)) * 8;  // T2 read-side XOR
  f32x4 acc[MR][4] = {};

#define SA(S, q)                                                              \
  {                                                                           \
    const bf16_t* g = gA + (size_t)(q) * 32;                                  \
    bf16_t* l = &lds[S][(w * (MR * 8)) * 32];                                 \
    gload_lds16(g, l);                                                        \
    if constexpr (MR == 4) gload_lds16(g + (size_t)16 * lda, l + 16 * 32);    \
  }
#define SB(S, q)                                                              \
  {                                                                           \
    const bf16_t* g = gB + (size_t)(q) * 32;                                  \
    bf16_t* l = &lds[S][BM * 32 + (w * 32) * 32];                             \
    gload_lds16(g, l);                                                        \
    gload_lds16(g + (size_t)16 * ldb, l + 16 * 32);                           \
  }
#define VMW0 asm volatile("s_waitcnt vmcnt(0)" ::: "memory")
#define LKW asm volatile("s_waitcnt lgkmcnt(0)" ::: "memory")
#define BAR __builtin_amdgcn_s_barrier()

  const int NT = K >> 5;

  // prologue: stage tile 0 -> slot 0
  SA(0, 0); SB(0, 0);
  VMW0;
  BAR;

  for (int q = 0; q < NT; ++q) {
    const int s = q & 1;
    if (q + 1 < NT) {
      SA(s ^ 1, q + 1);
      SB(s ^ 1, q + 1);
    }
    bf16x8 af[MR], bfr[4];
#pragma unroll
    for (int j = 0; j < 4; ++j)
      bfr[j] = *reinterpret_cast<const bf16x8*>(
          &lds[s][BM * 32 + (wc * 64 + j * 16 + rsel) * 32 + kswz]);
#pragma unroll
    for (int i = 0; i < MR; ++i)
      af[i] = *reinterpret_cast<const bf16x8*>(
          &lds[s][(wr * (MR * 16) + i * 16 + rsel) * 32 + kswz]);
    __builtin_amdgcn_s_setprio(1);
#pragma unroll
    for (int i = 0; i < MR; ++i)
#pragma unroll
      for (int j = 0; j < 4; ++j)
        acc[i][j] = __builtin_amdgcn_mfma_f32_16x16x32_bf16(
            af[i], bfr[j], acc[i][j], 0, 0, 0);
    __builtin_amdgcn_s_setprio(0);
    if (q + 1 < NT) {
      LKW;   // my frag reads of slot s retired -> slot s free after BAR
      VMW0;  // my stage loads for tile q+1 landed -> visible after BAR
      BAR;
    }
  }
#undef SA
#undef SB
#undef VMW0
#undef LKW
#undef BAR

  // epilogue: C/D layout col=lane&15, row=(lane>>4)*4+reg (m89-verified)
  const int rb = (lane >> 4) * 4, cs = lane & 15;
#pragma unroll
  for (int i = 0; i < MR; ++i) {
#pragma unroll
    for (int j = 0; j < 4; ++j) {
#pragma unroll
      for (int r = 0; r < 4; ++r) {
        const int row = m0 + wr * (MR * 16) + i * 16 + rb + r;
        const int col = n0 + wc * 64 + j * 16 + cs;
        float v2 = acc[i][j][r];
        if constexpr (EPI == 0) {
          const int seg = n0 >> 10;
          bf16_t* Cb = (bf16_t*)C + (size_t)seg * 8192 * 1024;
          const float scl = (seg == 0) ? 0.03125f : 1.0f;
          v2 = (v2 + bias[col]) * scl;
          Cb[(size_t)row * 1024 + (col & 1023)] = (bf16_t)v2;
        } else if constexpr (EPI == 1) {
          ((float*)C)[(size_t)bz * sC + (size_t)row * ldc + col] = v2;
        } else {
          ((_Float16*)C)[(size_t)bz * sC + (size_t)row * ldc + col] =
              (_Float16)v2;
        }
      }
    }
  }
}

// ---------------------------------------------------------------------------
// row softmax: S fp16 [8192 rows][2048] -> P bf16
// ---------------------------------------------------------------------------
__global__ __launch_bounds__(256) void softmax_k(
    const _Float16* __restrict__ S, bf16_t* __restrict__ P) {
  const long row = blockIdx.x;
  const _Float16* s = S + row * 2048;
  const int tid = threadIdx.x;
  const int wave = tid >> 6, lane = tid & 63;

  float v[8];
  {
    f16x8 hv = *reinterpret_cast<const f16x8*>(s + tid * 8);
#pragma unroll
    for (int k = 0; k < 8; ++k) v[k] = (float)hv[k];
  }
  float m = v[0];
#pragma unroll
  for (int k = 1; k < 8; ++k) m = fmaxf(m, v[k]);
#pragma unroll
  for (int off = 32; off; off >>= 1) m = fmaxf(m, __shfl_xor(m, off));

  __shared__ float red[8];
  if (lane == 0) red[wave] = m;
  __syncthreads();
  m = fmaxf(fmaxf(red[0], red[1]), fmaxf(red[2], red[3]));

  float e[8], sum = 0.f;
#pragma unroll
  for (int k = 0; k < 8; ++k) { e[k] = __expf(v[k] - m); sum += e[k]; }
#pragma unroll
  for (int off = 32; off; off >>= 1) sum += __shfl_xor(sum, off);
  if (lane == 0) red[4 + wave] = sum;
  __syncthreads();
  sum = red[4] + red[5] + red[6] + red[7];
  const float inv = 1.0f / sum;

  bf16x8 o;
#pragma unroll
  for (int k = 0; k < 8; ++k) o[k] = (bf16_t)(e[k] * inv);
  *reinterpret_cast<bf16x8*>(P + row * 2048 + tid * 8) = o;
}

// ---------------------------------------------------------------------------
// launch
// ---------------------------------------------------------------------------
extern "C" void kernel_launch(void* const* d_in, const int* in_sizes, int n_in,
                              void* d_out, int out_size, void* d_ws,
                              size_t ws_size, hipStream_t stream) {
  const float* x = (const float*)d_in[0];  // [4,2048,1024]
  const float* W = (const float*)d_in[1];  // [1024,3072]
  const float* b = (const float*)d_in[2];  // [3072]
  float* out = (float*)d_out;              // [4,2048,1024] fp32

  char* w = (char*)d_ws;
  bf16_t* xb = (bf16_t*)w;    w += (size_t)8192 * 1024 * 2;
  bf16_t* Wt = (bf16_t*)w;    w += (size_t)3072 * 1024 * 2;
  bf16_t* QKV = (bf16_t*)w;   w += (size_t)3 * 8192 * 1024 * 2;
  bf16_t* Vt = (bf16_t*)w;    w += (size_t)4 * 1024 * 2048 * 2;
  _Float16* S = (_Float16*)w; w += (size_t)4 * 2048 * 2048 * 2;
  bf16_t* P = (bf16_t*)w;     w += (size_t)4 * 2048 * 2048 * 2;

  bf16_t* Q = QKV;
  bf16_t* Kd = QKV + (size_t)8192 * 1024;
  bf16_t* V = QKV + (size_t)2 * 8192 * 1024;

  cast_f32_bf16<<<8192, 256, 0, stream>>>(x, xb, (long)8192 * 1024);
  transpose_W<<<dim3(48, 16), 256, 0, stream>>>(W, Wt);

  // Q|K|V dense = x @ W + b (Q scaled 1/32). grid 24x64 = 1536 blocks
  gemm_roll<0, 4><<<dim3(24, 64, 1), 256, 0, stream>>>(
      xb, Wt, QKV, b, 1024, 1024, 1024, 0, 0, 0, 1024);

  transpose_V<<<dim3(16, 32, 4), 256, 0, stream>>>(V, Vt);

  // S = Qs @ K^T, fp16 out. grid 16x16x4 = 1024 blocks (4/CU, no tail)
  gemm_roll<2, 4><<<dim3(16, 16, 4), 256, 0, stream>>>(
      Q, Kd, S, nullptr, 1024, 1024, 2048,
      (long)2048 * 1024, (long)2048 * 1024, (long)2048 * 2048, 1024);

  softmax_k<<<8192, 256, 0, stream>>>(S, P);

  // out = P @ Vt^T, fp32 out. BM=64: grid 8x32x4 = 1024 blocks (4/CU)
  gemm_roll<1, 2><<<dim3(8, 32, 4), 256, 0, stream>>>(
      P, Vt, out, nullptr, 2048, 2048, 1024,
      (long)2048 * 2048, (long)1024 * 2048, (long)2048 * 1024, 2048);
}